// Round 5
// baseline (1053.899 us; speedup 1.0000x reference)
//
#include <hip/hip_runtime.h>
#include <math.h>

// CIN (xDeepFM) — split-bf16 MFMA, register-direct W (no LDS staging, no hot-loop barriers).
// y[b,o,d] = bias[o] + sum_f x[b,f,d] * ( sum_h W[o,f*H+h] * h_in[b,h,d] )
// Inner sum: 16x16x32 bf16 MFMA, W and h each split hi+lo bf16 (3 terms, lo*lo dropped).
// A-frags (W) are plain global loads from a fragment-linear split image (L2-resident);
// B-frags (h) are per-pass register-resident; LDS holds only the 8KB x scale tile.
// B=512, F=32, D=64, O=128; H0=32 (h=x), H1=H2=128.

typedef __attribute__((ext_vector_type(8))) short bf16x8;
typedef __attribute__((ext_vector_type(4))) float f32x4;
typedef __attribute__((ext_vector_type(4))) unsigned short u16x4;

#define HT_LO 4194304   // shorts: 512*64*128 (offset of lo plane)

__device__ __forceinline__ unsigned short f2bf(float f) {
  unsigned int u = __float_as_uint(f);
  u = (u + 0x7fffu + ((u >> 16) & 1u)) >> 16;   // RNE
  return (unsigned short)u;
}
__device__ __forceinline__ float bf2f(unsigned short h) {
  return __uint_as_float((unsigned int)h << 16);
}

__device__ __forceinline__ void gll16(const void* g, void* l) {
  __builtin_amdgcn_global_load_lds(
      (const __attribute__((address_space(1))) unsigned int*)g,
      (__attribute__((address_space(3))) unsigned int*)l, 16, 0, 0);
}

// ---- pre-pass: repack W (fp32, row-major 128xK) into split-bf16 image,
// chunk-sequential in iteration order: chunk = pass*32 + f.
// chunk layout (16B units): [s in {hi,lo}][ksl][idx = mt*64 + lane]
// element: W[o = mt*16+(lane&15)][c = f*H + pass*(KSP*32) + ksl*32 + g*8 + j]
__global__ void repack_w_kernel(const float* __restrict__ W, unsigned short* __restrict__ dst,
                                int H, int KSP, int nunits)
{
  const int t = blockIdx.x * 256 + threadIdx.x;
  if (t >= nunits) return;
  const int K = 32 * H;
  const int CU_ = 2 * KSP * 512;          // 16B units per chunk
  const int chunk = t / CU_;
  const int pass = chunk >> 5, f = chunk & 31;
  int r = t % CU_;
  const int s = r / (KSP * 512); r %= (KSP * 512);
  const int ksl = r >> 9;
  const int idx = r & 511;
  const int o = (idx >> 6) * 16 + (idx & 15);
  const int c = f * H + pass * (KSP * 32) + ksl * 32 + ((idx >> 4) & 3) * 8;
  const float* src = W + (size_t)o * K + c;
  u16x4 a, bq;
#pragma unroll
  for (int j = 0; j < 4; ++j) {
    float v = src[j];
    unsigned short hb = f2bf(v);
    a[j] = (s == 0) ? hb : f2bf(v - bf2f(hb));
    v = src[4 + j];
    hb = f2bf(v);
    bq[j] = (s == 0) ? hb : f2bf(v - bf2f(hb));
  }
  *(u16x4*)(dst + (size_t)t * 8)     = a;
  *(u16x4*)(dst + (size_t)t * 8 + 4) = bq;
}

// ---- main layer kernel ----
// grid 1024 x 256 threads; block = (b = blk>>1, o-half = blk&1); wave w owns
// o-tile mt = (blk&1)*4 + w, i.e. o in [mt*16, mt*16+16), all 4 d-tiles.
// LDS: 8KB raw x[b] only. One barrier total (publishes x).
template<int H, int NPASS, int KSP, bool FIRST, bool STORE_H>
__global__ __launch_bounds__(256, 4) void cin_mfma_layer(
    const unsigned short* __restrict__ Wimg,
    const float* __restrict__ x,               // (B,32,64) fp32
    const unsigned short* __restrict__ hTin,   // hi plane; lo at +HT_LO (null if FIRST)
    const float* __restrict__ bias,
    unsigned short* __restrict__ hTout,        // hi plane; lo at +HT_LO
    float* __restrict__ outs, int col_off)
{
  constexpr int CHUNK16 = 2 * KSP * 512;       // 16B units per (pass,f) chunk
  __shared__ char lds[8192];
  const int tid = threadIdx.x;
  const int w = tid >> 6, l = tid & 63, g = l >> 4, li = l & 15;
  const int b  = blockIdx.x >> 1;
  const int mt = (blockIdx.x & 1) * 4 + w;     // global o-tile 0..7
  const int obase = mt * 16;
  const float* lx = (const float*)lds;

  // stage raw x[b] (8 KB, lane-linear, 2 rounds of 256 threads)
#pragma unroll
  for (int r = 0; r < 2; ++r)
    gll16(x + (size_t)b * 2048 + (r * 256 + tid) * 4, lds + r * 4096 + w * 1024);

  f32x4 Y[4];
#pragma unroll
  for (int nt = 0; nt < 4; ++nt) Y[nt] = (f32x4){0.f, 0.f, 0.f, 0.f};
  const f32x4 zero4 = (f32x4){0.f, 0.f, 0.f, 0.f};
  bf16x8 Bh[KSP][4], Bl[KSP][4];

  asm volatile("s_waitcnt vmcnt(0)" ::: "memory");
  __builtin_amdgcn_s_barrier();   // the ONLY barrier: publishes x[b] to all waves

  if constexpr (FIRST) {
    // build split B-fragments from raw x in LDS (h == x; KSP==1, NPASS==1)
#pragma unroll
    for (int nt = 0; nt < 4; ++nt) {
      union { bf16x8 v; unsigned short u[8]; } th, tl;
#pragma unroll
      for (int j = 0; j < 8; ++j) {
        const float xv = lx[(g * 8 + j) * 64 + nt * 16 + li];
        const unsigned short hb = f2bf(xv);
        th.u[j] = hb;
        tl.u[j] = f2bf(xv - bf2f(hb));
      }
      Bh[0][nt] = th.v;
      Bl[0][nt] = tl.v;
    }
  }

  // this wave's A-fragment base in the image (16B units)
  const bf16x8* Wf = (const bf16x8*)Wimg + (mt * 64 + l);

#pragma unroll 1
  for (int pass = 0; pass < NPASS; ++pass) {
    if constexpr (!FIRST) {
      // B-fragments for this pass (reused across all 32 f)
#pragma unroll
      for (int ks = 0; ks < KSP; ++ks)
#pragma unroll
        for (int nt = 0; nt < 4; ++nt) {
          const size_t off = (size_t)b * 8192 + (size_t)(nt * 16 + li) * 128
                           + pass * (KSP * 32) + ks * 32 + g * 8;
          Bh[ks][nt] = *(const bf16x8*)(hTin + off);
          Bl[ks][nt] = *(const bf16x8*)(hTin + HT_LO + off);
        }
    }
    const bf16x8* Wp = Wf + (size_t)pass * 32 * CHUNK16;
#pragma unroll
    for (int f = 0; f < 32; ++f) {
      f32x4 G[4];
#pragma unroll
      for (int ks = 0; ks < KSP; ++ks) {
        const bf16x8 Ah = Wp[f * CHUNK16 + (0 * KSP + ks) * 512];
        const bf16x8 Al = Wp[f * CHUNK16 + (1 * KSP + ks) * 512];
#pragma unroll
        for (int nt = 0; nt < 4; ++nt) {
          G[nt] = __builtin_amdgcn_mfma_f32_16x16x32_bf16(Ah, Bh[ks][nt],
                      (ks == 0) ? zero4 : G[nt], 0, 0, 0);
          G[nt] = __builtin_amdgcn_mfma_f32_16x16x32_bf16(Ah, Bl[ks][nt], G[nt], 0, 0, 0);
          G[nt] = __builtin_amdgcn_mfma_f32_16x16x32_bf16(Al, Bh[ks][nt], G[nt], 0, 0, 0);
        }
      }
#pragma unroll
      for (int nt = 0; nt < 4; ++nt) {
        const float sc = lx[f * 64 + nt * 16 + li];   // fp32 x-scale (broadcast read)
        Y[nt] += G[nt] * sc;
      }
    }
  }

  // ---- epilogue: bias, split-hT store, outs row-sums ----
  // lane holds y[o = obase + g*4 + j][d = nt*16 + li]
  const f32x4 bv = *(const f32x4*)(bias + obase + g * 4);
#pragma unroll
  for (int nt = 0; nt < 4; ++nt) Y[nt] += bv;

  if constexpr (STORE_H) {
#pragma unroll
    for (int nt = 0; nt < 4; ++nt) {
      const int d = nt * 16 + li;
      u16x4 ph, pl;
#pragma unroll
      for (int j = 0; j < 4; ++j) {
        const unsigned short hb = f2bf(Y[nt][j]);
        ph[j] = hb;
        pl[j] = f2bf(Y[nt][j] - bf2f(hb));
      }
      const size_t off = (size_t)b * 8192 + (size_t)d * 128 + obase + g * 4;
      *(u16x4*)(hTout + off)         = ph;
      *(u16x4*)(hTout + HT_LO + off) = pl;
    }
  }

  {
    f32x4 s = Y[0] + Y[1] + Y[2] + Y[3];
#pragma unroll
    for (int m = 1; m < 16; m <<= 1) {
      s.x += __shfl_xor(s.x, m, 16);
      s.y += __shfl_xor(s.y, m, 16);
      s.z += __shfl_xor(s.z, m, 16);
      s.w += __shfl_xor(s.w, m, 16);
    }
    if (li == 0)
      *(f32x4*)(outs + (size_t)b * 384 + col_off + obase + g * 4) = s;
  }
}

// ---- final: out[b] = sigmoid( relu(outs[b,:]) . Wout + bout ) ----
__global__ __launch_bounds__(64) void cin_final_kernel(
    const float* __restrict__ outs, const float* __restrict__ Wout,
    const float* __restrict__ bout, float* __restrict__ out)
{
  const int b = blockIdx.x;
  const int lane = threadIdx.x;
  float p = 0.f;
  for (int j = lane; j < 384; j += 64) {
    float v = outs[(size_t)b * 384 + j];
    v = v > 0.f ? v : 0.f;
    p = fmaf(v, Wout[j], p);
  }
#pragma unroll
  for (int m = 32; m; m >>= 1) p += __shfl_xor(p, m, 64);
  if (lane == 0) {
    const float t = p + bout[0];
    out[b] = 1.f / (1.f + expf(-t));
  }
}

extern "C" void kernel_launch(void* const* d_in, const int* in_sizes, int n_in,
                              void* d_out, int out_size, void* d_ws, size_t ws_size,
                              hipStream_t stream)
{
  const float* x    = (const float*)d_in[0];
  const float* W0   = (const float*)d_in[1];
  const float* b0   = (const float*)d_in[2];
  const float* W1   = (const float*)d_in[3];
  const float* b1   = (const float*)d_in[4];
  const float* W2   = (const float*)d_in[5];
  const float* b2   = (const float*)d_in[6];
  const float* Wout = (const float*)d_in[7];
  const float* bout = (const float*)d_in[8];
  float* out = (float*)d_out;

  char* ws = (char*)d_ws;
  unsigned short* hT1  = (unsigned short*)ws;                    // 16 MB (hi+lo)
  unsigned short* hT2  = (unsigned short*)(ws + (16 << 20));     // 16 MB
  float*          outs = (float*)        (ws + (32 << 20));      // 768 KB
  unsigned short* Wi0  = (unsigned short*)(ws + (33 << 20));               // 512 KB
  unsigned short* Wi1  = (unsigned short*)(ws + (33 << 20) + (1 << 19));   // 2 MB
  unsigned short* Wi2  = (unsigned short*)(ws + (33 << 20) + (1 << 19) + (2 << 20)); // 2 MB

  // nunits = O*K*2 / 8 (16B units of the split image)
  repack_w_kernel<<<128, 256, 0, stream>>>(W0, Wi0, 32,  1, 32768);
  repack_w_kernel<<<512, 256, 0, stream>>>(W1, Wi1, 128, 2, 131072);
  repack_w_kernel<<<512, 256, 0, stream>>>(W2, Wi2, 128, 2, 131072);

  cin_mfma_layer<32,  1, 1, true,  true ><<<1024, 256, 0, stream>>>(Wi0, x, nullptr, b0, hT1, outs, 0);
  cin_mfma_layer<128, 2, 2, false, true ><<<1024, 256, 0, stream>>>(Wi1, x, hT1,    b1, hT2, outs, 128);
  cin_mfma_layer<128, 2, 2, false, false><<<1024, 256, 0, stream>>>(Wi2, x, hT2,    b2, nullptr, outs, 256);

  cin_final_kernel<<<512, 64, 0, stream>>>(outs, Wout, bout, out);
}

// Round 6
// 214.107 us; speedup vs baseline: 4.9223x; 4.9223x over previous
//
#include <hip/hip_runtime.h>
#include <math.h>

// CIN (xDeepFM) — split-bf16 MFMA, round-3 structure with dead barriers removed.
// y[b,o,d] = bias[o] + sum_f x[b,f,d] * ( sum_h W[o,f*H+h] * h_in[b,h,d] )
// Inner sum: 16x16x32 bf16 MFMA with W,h each split hi+lo bf16:
//   W*h ~= Whi*hhi + Whi*hlo + Wlo*hhi   (lo*lo dropped, ~2^-18 rel)
// Wave w stages and reads ONLY LDS bytes [r*8192 + w*1024, +1024) of each W
// chunk -> no cross-wave LDS sharing for W. The only shared LDS data is the
// 8KB x-tile, published by ONE prologue vmcnt(0)+barrier. All f-loop barriers
// removed; per-wave counted vmcnt(SR) is the only staging synchronization.
// B=512, F=32, D=64, O=128; H0=32 (h=x), H1=H2=128.

typedef __attribute__((ext_vector_type(8))) short bf16x8;
typedef __attribute__((ext_vector_type(4))) float f32x4;
typedef __attribute__((ext_vector_type(4))) unsigned short u16x4;

#define HT_LO 4194304   // shorts: 512*64*128 (offset of lo plane)

__device__ __forceinline__ unsigned short f2bf(float f) {
  unsigned int u = __float_as_uint(f);
  u = (u + 0x7fffu + ((u >> 16) & 1u)) >> 16;   // RNE
  return (unsigned short)u;
}
__device__ __forceinline__ float bf2f(unsigned short h) {
  return __uint_as_float((unsigned int)h << 16);
}

__device__ __forceinline__ void gll16(const void* g, void* l) {
  __builtin_amdgcn_global_load_lds(
      (const __attribute__((address_space(1))) unsigned int*)g,
      (__attribute__((address_space(3))) unsigned int*)l, 16, 0, 0);
}

// ---- pre-pass: repack W (fp32, row-major 128xK) into bf16 split fragment-linear image.
// f-chunk layout (16B units): [s in {hi,lo}][ksl][idx=mt*64+lane]
// element: W[o = mt*16+(l&15)][c = f*H + pass*64*KSP/2... see round 3] — unchanged.
__global__ void repack_w_kernel(const float* __restrict__ W, unsigned short* __restrict__ dst,
                                int H, int NP, int KSP, int nchunks)
{
  const int t = blockIdx.x * 256 + threadIdx.x;
  if (t >= nchunks) return;
  const int K = 32 * H;
  const int cpf = NP * KSP * 512;
  const int f = t / cpf;
  int r = t % cpf;
  const int pass = r / (KSP * 512); r %= (KSP * 512);
  const int ksl = r / 512;
  const int idx = r % 512;
  const int mt = idx >> 6, l = idx & 63;
  const int o = mt * 16 + (l & 15);
  const int c = f * H + pass * 64 + ksl * 32 + (l >> 4) * 8;
  const float* s = W + (size_t)o * K + c;
  u16x4 h0, h1, l0, l1;
#pragma unroll
  for (int j = 0; j < 4; ++j) {
    float v = s[j];
    unsigned short hb = f2bf(v);
    h0[j] = hb; l0[j] = f2bf(v - bf2f(hb));
    v = s[4 + j];
    hb = f2bf(v);
    h1[j] = hb; l1[j] = f2bf(v - bf2f(hb));
  }
  const size_t chunk_hi = ((size_t)((f * NP + pass) * 2 + 0) * KSP + ksl) * 512 + idx;
  const size_t chunk_lo = ((size_t)((f * NP + pass) * 2 + 1) * KSP + ksl) * 512 + idx;
  *(u16x4*)(dst + chunk_hi * 8)     = h0;
  *(u16x4*)(dst + chunk_hi * 8 + 4) = h1;
  *(u16x4*)(dst + chunk_lo * 8)     = l0;
  *(u16x4*)(dst + chunk_lo * 8 + 4) = l1;
}

// ---- main layer kernel ----
// grid 512 blocks x 512 threads; block b. Wave w owns o in [16w, 16w+16).
// LDS: [0, 2*CHUNK) = W chunk double buffer; [2*CHUNK, +8KB) = raw x[b].
template<int H, int NPASS, int KSP, bool FIRST, bool STORE_H>
__global__ __launch_bounds__(512) void cin_mfma_layer(
    const unsigned short* __restrict__ Wimg,
    const float* __restrict__ x,               // (B,32,64) fp32
    const unsigned short* __restrict__ hTin,   // hi plane; lo at +HT_LO  (null if FIRST)
    const float* __restrict__ bias,
    unsigned short* __restrict__ hTout,        // hi plane; lo at +HT_LO
    float* __restrict__ outs, int col_off)
{
  constexpr int CHUNK = 2 * KSP * 8192;        // bytes per f-chunk (hi+lo)
  constexpr int SR = 2 * KSP;                  // staging rounds per chunk
  constexpr int XOFF = 2 * CHUNK;
  __shared__ char lds[2 * CHUNK + 8192];
  const int tid = threadIdx.x;
  const int w = tid >> 6, l = tid & 63, g = l >> 4, li = l & 15;
  const int b = blockIdx.x;
  const float* lx = (const float*)(lds + XOFF);

  // stage raw x[b] (8 KB, lane-linear)
  gll16(x + (size_t)b * 2048 + tid * 4, lds + XOFF + (w * 64) * 16);

  f32x4 Y[4];
#pragma unroll
  for (int nt = 0; nt < 4; ++nt) Y[nt] = (f32x4){0.f, 0.f, 0.f, 0.f};
  const f32x4 zero4 = (f32x4){0.f, 0.f, 0.f, 0.f};

  bf16x8 Bh[KSP][4], Bl[KSP][4];
  int cur = 0;

  for (int pass = 0; pass < NPASS; ++pass) {
    if constexpr (!FIRST) {
      // B-fragments for this pass (reused across all 32 f)
#pragma unroll
      for (int ks = 0; ks < KSP; ++ks)
#pragma unroll
        for (int nt = 0; nt < 4; ++nt) {
          const int d = nt * 16 + li;
          const size_t off = (size_t)b * 8192 + d * 128 + pass * 64 + ks * 32 + g * 8;
          Bh[ks][nt] = *(const bf16x8*)(hTin + off);
          Bl[ks][nt] = *(const bf16x8*)(hTin + HT_LO + off);
        }
    }
    // stage W chunk (f=0, pass) into buf cur
    {
      const char* src = (const char*)Wimg + (size_t)(0 * NPASS + pass) * CHUNK;
#pragma unroll
      for (int r = 0; r < SR; ++r)
        gll16(src + (size_t)(r * 512 + tid) * 16,
              lds + cur * CHUNK + (r * 512 + w * 64) * 16);
    }
    if (pass == 0) {
      // the ONLY barrier: publishes the shared x-tile (and first chunk) to all waves
      asm volatile("s_waitcnt vmcnt(0)" ::: "memory");
      __builtin_amdgcn_s_barrier();
    }

    if constexpr (FIRST) {
      // build split B-fragments from raw x in LDS (pass 0 only; NPASS==1)
#pragma unroll
      for (int nt = 0; nt < 4; ++nt) {
        union { bf16x8 v; unsigned short u[8]; } th, tl;
#pragma unroll
        for (int j = 0; j < 8; ++j) {
          const float xv = lx[(g * 8 + j) * 64 + nt * 16 + li];
          const unsigned short hb = f2bf(xv);
          th.u[j] = hb;
          tl.u[j] = f2bf(xv - bf2f(hb));
        }
        Bh[0][nt] = th.v;
        Bl[0][nt] = tl.v;
      }
    }

    for (int f = 0; f < 32; ++f) {
      if (f < 31) {
        // prefetch W chunk for f+1 into the other buffer; counted per-wave wait
        const char* src = (const char*)Wimg + (size_t)((f + 1) * NPASS + pass) * CHUNK;
#pragma unroll
        for (int r = 0; r < SR; ++r)
          gll16(src + (size_t)(r * 512 + tid) * 16,
                lds + (cur ^ 1) * CHUNK + (r * 512 + w * 64) * 16);
        asm volatile("s_waitcnt vmcnt(%0)" :: "i"(SR) : "memory");
      } else {
        asm volatile("s_waitcnt vmcnt(0)" ::: "memory");
      }
      // NO barrier: wave w reads only the LDS bytes it staged itself.

      f32x4 G[4];
      __builtin_amdgcn_s_setprio(1);
#pragma unroll
      for (int ks = 0; ks < KSP; ++ks) {
        const bf16x8 Ah = *(const bf16x8*)(lds + cur * CHUNK + (((0 * KSP + ks) * 8 + w) * 64 + l) * 16);
        const bf16x8 Al = *(const bf16x8*)(lds + cur * CHUNK + (((1 * KSP + ks) * 8 + w) * 64 + l) * 16);
#pragma unroll
        for (int nt = 0; nt < 4; ++nt) {
          G[nt] = __builtin_amdgcn_mfma_f32_16x16x32_bf16(Ah, Bh[ks][nt],
                      (ks == 0) ? zero4 : G[nt], 0, 0, 0);
          G[nt] = __builtin_amdgcn_mfma_f32_16x16x32_bf16(Ah, Bl[ks][nt], G[nt], 0, 0, 0);
          G[nt] = __builtin_amdgcn_mfma_f32_16x16x32_bf16(Al, Bh[ks][nt], G[nt], 0, 0, 0);
        }
      }
      __builtin_amdgcn_s_setprio(0);
#pragma unroll
      for (int nt = 0; nt < 4; ++nt) {
        const float sc = lx[f * 64 + nt * 16 + li];   // fp32 x-scale (broadcast read)
        Y[nt] += G[nt] * sc;
      }
      cur ^= 1;
    }
  }

  // ---- epilogue: bias, split-hT store, outs row-sums ----
  const f32x4 bv = *(const f32x4*)(bias + w * 16 + g * 4);
#pragma unroll
  for (int nt = 0; nt < 4; ++nt) Y[nt] += bv;

  if constexpr (STORE_H) {
#pragma unroll
    for (int nt = 0; nt < 4; ++nt) {
      const int d = nt * 16 + li;
      u16x4 ph, pl;
#pragma unroll
      for (int j = 0; j < 4; ++j) {
        const unsigned short hb = f2bf(Y[nt][j]);
        ph[j] = hb;
        pl[j] = f2bf(Y[nt][j] - bf2f(hb));
      }
      const size_t off = (size_t)b * 8192 + (size_t)d * 128 + w * 16 + g * 4;
      *(u16x4*)(hTout + off)         = ph;
      *(u16x4*)(hTout + HT_LO + off) = pl;
    }
  }

  {
    f32x4 s = Y[0] + Y[1] + Y[2] + Y[3];
#pragma unroll
    for (int m = 1; m < 16; m <<= 1) {
      s.x += __shfl_xor(s.x, m, 16);
      s.y += __shfl_xor(s.y, m, 16);
      s.z += __shfl_xor(s.z, m, 16);
      s.w += __shfl_xor(s.w, m, 16);
    }
    if (li == 0)
      *(f32x4*)(outs + (size_t)b * 384 + col_off + w * 16 + g * 4) = s;
  }
}

// ---- final: out[b] = sigmoid( relu(outs[b,:]) . Wout + bout ) ----
__global__ __launch_bounds__(64) void cin_final_kernel(
    const float* __restrict__ outs, const float* __restrict__ Wout,
    const float* __restrict__ bout, float* __restrict__ out)
{
  const int b = blockIdx.x;
  const int lane = threadIdx.x;
  float p = 0.f;
  for (int j = lane; j < 384; j += 64) {
    float v = outs[(size_t)b * 384 + j];
    v = v > 0.f ? v : 0.f;
    p = fmaf(v, Wout[j], p);
  }
#pragma unroll
  for (int m = 32; m; m >>= 1) p += __shfl_xor(p, m, 64);
  if (lane == 0) {
    const float t = p + bout[0];
    out[b] = 1.f / (1.f + expf(-t));
  }
}

extern "C" void kernel_launch(void* const* d_in, const int* in_sizes, int n_in,
                              void* d_out, int out_size, void* d_ws, size_t ws_size,
                              hipStream_t stream)
{
  const float* x    = (const float*)d_in[0];
  const float* W0   = (const float*)d_in[1];
  const float* b0   = (const float*)d_in[2];
  const float* W1   = (const float*)d_in[3];
  const float* b1   = (const float*)d_in[4];
  const float* W2   = (const float*)d_in[5];
  const float* b2   = (const float*)d_in[6];
  const float* Wout = (const float*)d_in[7];
  const float* bout = (const float*)d_in[8];
  float* out = (float*)d_out;

  char* ws = (char*)d_ws;
  unsigned short* hT1  = (unsigned short*)ws;                    // 16 MB (hi+lo)
  unsigned short* hT2  = (unsigned short*)(ws + (16 << 20));     // 16 MB
  float*          outs = (float*)        (ws + (32 << 20));      // 768 KB
  unsigned short* Wi0  = (unsigned short*)(ws + (33 << 20));               // 512 KB
  unsigned short* Wi1  = (unsigned short*)(ws + (33 << 20) + (1 << 19));   // 2 MB
  unsigned short* Wi2  = (unsigned short*)(ws + (33 << 20) + (1 << 19) + (2 << 20)); // 2 MB

  repack_w_kernel<<<64,  256, 0, stream>>>(W0, Wi0, 32,  1, 1, 16384);
  repack_w_kernel<<<256, 256, 0, stream>>>(W1, Wi1, 128, 2, 2, 65536);
  repack_w_kernel<<<256, 256, 0, stream>>>(W2, Wi2, 128, 2, 2, 65536);

  cin_mfma_layer<32,  1, 1, true,  true ><<<512, 512, 0, stream>>>(Wi0, x, nullptr, b0, hT1, outs, 0);
  cin_mfma_layer<128, 2, 2, false, true ><<<512, 512, 0, stream>>>(Wi1, x, hT1,    b1, hT2, outs, 128);
  cin_mfma_layer<128, 2, 2, false, false><<<512, 512, 0, stream>>>(Wi2, x, hT2,    b2, nullptr, outs, 256);

  cin_final_kernel<<<512, 64, 0, stream>>>(outs, Wout, bout, out);
}